// Round 6
// baseline (1903.399 us; speedup 1.0000x reference)
//
#include <hip/hip_runtime.h>
#include <math.h>

#define B_    32
#define T_    512
#define WDIM_ 300
#define H_    256
#define G4_   1024            // 4*H
#define M_    (B_ * T_)       // 16384

// persistent-LSTM geometry: team = 8 WGs covering one (dir, batch-pair)
#define NCG   8               // col groups per team (32 d's each)
#define NWG   256             // 2 dirs * 16 batch-pairs * NCG
#define THR   512
#define HXN   (2 * 2 * B_ * H_)   // packets: [buf][dir][32][256]

// repeat macros -> compile-time-constant indices (SROA-safe register arrays)
#define RPT4(M, b)  M(b) M((b)+1) M((b)+2) M((b)+3)
#define RPT16(M, b) RPT4(M, b) RPT4(M, (b)+4) RPT4(M, (b)+8) RPT4(M, (b)+12)
#define RPT64(M)    RPT16(M, 0) RPT16(M, 16) RPT16(M, 32) RPT16(M, 48)

// fast gate math: v_exp_f32 + v_rcp_f32 (|rel err| ~1e-6, threshold 8e-4)
__device__ __forceinline__ float fsigm(float x) {
    return __builtin_amdgcn_rcpf(1.f + __expf(-x));
}
__device__ __forceinline__ float ftanh(float x) {
    const float ax = fabsf(x);
    const float t  = 1.f - 2.f * __builtin_amdgcn_rcpf(__expf(2.f * ax) + 1.f);
    return copysignf(t, x);
}

// ---------------------------------------------------------------------------
// Kernel 1: z = relu(emb[x] @ W_in + b_in)   [16384,300]@[300,256]
// ---------------------------------------------------------------------------
__global__ __launch_bounds__(256)
void k_embed_proj(const float* __restrict__ emb, const float* __restrict__ Win,
                  const float* __restrict__ bin, const int* __restrict__ x,
                  float* __restrict__ z)
{
    __shared__ float Ash[16][132];
    __shared__ float Bsh[16][132];
    __shared__ int   rows[128];

    const int tid = threadIdx.x;
    const int tx = tid & 15, ty = tid >> 4;
    const int rm = blockIdx.y * 128;
    const int cn = blockIdx.x * 128;

    if (tid < 128) rows[tid] = x[rm + tid];
    __syncthreads();

    float acc[8][8];
#pragma unroll
    for (int i = 0; i < 8; ++i)
#pragma unroll
        for (int j = 0; j < 8; ++j) acc[i][j] = 0.f;

    for (int kc = 0; kc < 19; ++kc) {
        const int k0 = kc * 16;
#pragma unroll
        for (int e = 0; e < 8; ++e) {
            const int idx = e * 256 + tid;
            const int r = idx >> 4, kk = idx & 15;
            const int k = k0 + kk;
            const int v = rows[r];
            Ash[kk][r] = (k < WDIM_) ? emb[(size_t)v * WDIM_ + k] : 0.f;
        }
#pragma unroll
        for (int e = 0; e < 8; ++e) {
            const int idx = e * 256 + tid;
            const int kk = idx >> 7, n = idx & 127;
            const int k = k0 + kk;
            Bsh[kk][n] = (k < WDIM_) ? Win[(size_t)k * H_ + cn + n] : 0.f;
        }
        __syncthreads();
#pragma unroll
        for (int kk = 0; kk < 16; ++kk) {
            float a[8], bb[8];
#pragma unroll
            for (int i = 0; i < 8; ++i) a[i] = Ash[kk][ty * 8 + i];
#pragma unroll
            for (int j = 0; j < 8; ++j) bb[j] = Bsh[kk][tx * 8 + j];
#pragma unroll
            for (int i = 0; i < 8; ++i)
#pragma unroll
                for (int j = 0; j < 8; ++j) acc[i][j] += a[i] * bb[j];
        }
        __syncthreads();
    }

#pragma unroll
    for (int i = 0; i < 8; ++i) {
        const int row = rm + ty * 8 + i;
#pragma unroll
        for (int j = 0; j < 8; ++j) {
            const int col = cn + tx * 8 + j;
            z[(size_t)row * H_ + col] = fmaxf(acc[i][j] + bin[col], 0.f);
        }
    }
}

// ---------------------------------------------------------------------------
// Kernel 2: P_d = z @ Wih_d + bl_d  (both directions via blockIdx.z)
// ---------------------------------------------------------------------------
__global__ __launch_bounds__(256)
void k_in_proj(const float* __restrict__ z,
               const float* __restrict__ Wf, const float* __restrict__ blf,
               const float* __restrict__ Wb, const float* __restrict__ blb,
               float* __restrict__ Pf, float* __restrict__ Pb)
{
    const float* W  = blockIdx.z ? Wb  : Wf;
    const float* bl = blockIdx.z ? blb : blf;
    float*       P  = blockIdx.z ? Pb  : Pf;

    __shared__ float Ash[16][132];
    __shared__ float Bsh[16][132];

    const int tid = threadIdx.x;
    const int tx = tid & 15, ty = tid >> 4;
    const int rm = blockIdx.y * 128;
    const int cn = blockIdx.x * 128;

    float acc[8][8];
#pragma unroll
    for (int i = 0; i < 8; ++i)
#pragma unroll
        for (int j = 0; j < 8; ++j) acc[i][j] = 0.f;

    for (int kc = 0; kc < 16; ++kc) {
        const int k0 = kc * 16;
#pragma unroll
        for (int e = 0; e < 8; ++e) {
            const int idx = e * 256 + tid;
            const int r = idx >> 4, kk = idx & 15;
            Ash[kk][r] = z[(size_t)(rm + r) * H_ + k0 + kk];
        }
#pragma unroll
        for (int e = 0; e < 8; ++e) {
            const int idx = e * 256 + tid;
            const int kk = idx >> 7, n = idx & 127;
            Bsh[kk][n] = W[(size_t)(k0 + kk) * G4_ + cn + n];
        }
        __syncthreads();
#pragma unroll
        for (int kk = 0; kk < 16; ++kk) {
            float a[8], bb[8];
#pragma unroll
            for (int i = 0; i < 8; ++i) a[i] = Ash[kk][ty * 8 + i];
#pragma unroll
            for (int j = 0; j < 8; ++j) bb[j] = Bsh[kk][tx * 8 + j];
#pragma unroll
            for (int i = 0; i < 8; ++i)
#pragma unroll
                for (int j = 0; j < 8; ++j) acc[i][j] += a[i] * bb[j];
        }
        __syncthreads();
    }

#pragma unroll
    for (int i = 0; i < 8; ++i) {
        const int row = rm + ty * 8 + i;
#pragma unroll
        for (int j = 0; j < 8; ++j) {
            const int col = cn + tx * 8 + j;
            P[(size_t)row * G4_ + col] = acc[i][j] + bl[col];
        }
    }
}

// ---------------------------------------------------------------------------
// Init: zero h packet buffers ({h=0, tag=0} == initial state)
// ---------------------------------------------------------------------------
__global__ void k_init(unsigned long long* __restrict__ hx)
{
    const int i = blockIdx.x * blockDim.x + threadIdx.x;
    if (i < HXN) hx[i] = 0ull;
}

// ---------------------------------------------------------------------------
// Kernel 3: persistent bidirectional LSTM recurrence, fence-free, 1 chain
// barrier per step.  WG = (dir, batch-pair, colgroup of 32 hiddens).
// Lane layout (wave w, lane l): q=l>>4 (k-quarter), col_id=w*16+(l&15),
// hidden dloc=col_id>>2, gate=col_id&3.  The 4 k-partials of a column live
// in one wave -> shfl_xor(16,32) reduce; the 4 gate columns of a hidden are
// lane-adjacent -> 3 more shfls gather i/f/g/o.  Gates+publish happen
// per-wave right after its own GEMV (no cross-wave wait on the chain).
// Packets: {h,tag} 8-byte relaxed agent-scope atomics, parity
// double-buffered; stage-all -> barrier -> ... -> publish preserves the
// overwrite-safety invariant from R3/R4.
// ---------------------------------------------------------------------------
__global__ __launch_bounds__(THR, 2)
void k_lstm_persist(const float* __restrict__ Pf, const float* __restrict__ Pb,
                    const float* __restrict__ Whf, const float* __restrict__ Whb,
                    const int* __restrict__ lengths,
                    unsigned long long* __restrict__ hx,
                    float* __restrict__ pool)
{
    __shared__ float h_sh[2][256];    // [row][d] hidden state of the pair

    const int tid = threadIdx.x;
    const int wg  = blockIdx.x;
    const int bg  = wg & 15;
    const int dir = (wg >> 4) & 1;
    const int cg  = wg >> 5;          // 0..7 (teammates stride 32 -> same XCD)

    const float* P   = dir ? Pb  : Pf;
    const float* Whh = dir ? Whb : Whf;

    const int brow0 = bg * 2;
    const int len0 = lengths[brow0], len1 = lengths[brow0 + 1];
    const int tmax = max(len0, len1);

    const int lane   = tid & 63;
    const int w      = tid >> 6;          // wave 0..7
    const int q      = lane >> 4;         // k-quarter 0..3
    const int lo     = lane & 15;
    const int col_id = w * 16 + lo;       // 0..127
    const int dloc   = col_id >> 2;       // 0..31 local hidden
    const int g      = col_id & 3;        // gate (0=i,1=f,2=g,3=o)
    const int colg   = g * 256 + cg * 32 + dloc;   // global Whh column
    const int q64    = q * 64;

    // persistent W slice: 64 floats (constant indices only -> stays in regs)
    float wv[64];
    {
        const float* wp = Whh + (size_t)q64 * G4_ + colg;
#define LOADW(k) wv[k] = wp[(size_t)(k) * G4_];
        RPT64(LOADW)
#undef LOADW
    }

    // state (only meaningful on pub lanes: q==0 && gate==0)
    const bool pub = ((lane & 51) == 0);   // q==0 (bits 4:5) && g==0 (bits 0:1)
    float cst0 = 0.f, hreg0 = 0.f, pacc0 = 0.f;
    float cst1 = 0.f, hreg1 = 0.f, pacc1 = 0.f;

    // h-packet stage mapping (all 512 threads cover 2 rows x 256 cols)
    const int lrow = tid >> 8;
    const int ld   = tid & 255;
    const size_t bufStride = (size_t)2 * B_ * H_;   // packets per parity
    unsigned long long* slotR = hx + ((size_t)dir * 32 + brow0 + lrow) * 256 + ld;
    unsigned long long* slotW0 = hx + ((size_t)dir * 32 + brow0) * 256 + cg * 32 + dloc;
    unsigned long long* slotW1 = slotW0 + 256;

    for (int s = 0; s < tmax; ++s) {
        const int tt = dir ? (tmax - 1 - s) : s;

        // issue the packet poll-load first
        const unsigned long long* sp = slotR + (size_t)(s & 1) * bufStride;
        unsigned long long pk = __hip_atomic_load(sp, __ATOMIC_RELAXED,
                                                  __HIP_MEMORY_SCOPE_AGENT);

        // prefetch P rows for this step (pub lanes only need them)
        float pv00 = 0.f, pv01 = 0.f, pv02 = 0.f, pv03 = 0.f;
        float pv10 = 0.f, pv11 = 0.f, pv12 = 0.f, pv13 = 0.f;
        if (pub) {
            const float* pr0 = P + (size_t)(brow0 * T_ + tt) * G4_ + cg * 32 + dloc;
            const float* pr1 = pr0 + (size_t)T_ * G4_;
            pv00 = pr0[0]; pv01 = pr0[256]; pv02 = pr0[512]; pv03 = pr0[768];
            pv10 = pr1[0]; pv11 = pr1[256]; pv12 = pr1[512]; pv13 = pr1[768];
        }

        // poll h_{s-1} packets (tag >= s) and stage into LDS
        while ((unsigned)(pk >> 32) < (unsigned)s) {
            __builtin_amdgcn_s_sleep(1);
            pk = __hip_atomic_load(sp, __ATOMIC_RELAXED,
                                   __HIP_MEMORY_SCOPE_AGENT);
        }
        h_sh[lrow][ld] = __uint_as_float((unsigned)pk);
        __syncthreads();

        // GEMV: both rows, own column, k in [64q, 64q+64)
        float a0 = 0.f, a1 = 0.f;
        {
            const float* hp0 = &h_sh[0][q64];
            const float* hp1 = &h_sh[1][q64];
#define GEMV4(k4) { \
            const float4 hv0 = *(const float4*)(hp0 + 4 * (k4)); \
            const float4 hv1 = *(const float4*)(hp1 + 4 * (k4)); \
            a0 += hv0.x * wv[4*(k4)  ]; a1 += hv1.x * wv[4*(k4)  ]; \
            a0 += hv0.y * wv[4*(k4)+1]; a1 += hv1.y * wv[4*(k4)+1]; \
            a0 += hv0.z * wv[4*(k4)+2]; a1 += hv1.z * wv[4*(k4)+2]; \
            a0 += hv0.w * wv[4*(k4)+3]; a1 += hv1.w * wv[4*(k4)+3]; }
            RPT16(GEMV4, 0)
#undef GEMV4
        }

        // k-merge across quarters (lanes differing in bits 4,5)
        a0 += __shfl_xor(a0, 16); a0 += __shfl_xor(a0, 32);
        a1 += __shfl_xor(a1, 16); a1 += __shfl_xor(a1, 32);
        // gate gather: neighbors l^1, l^2, l^3 hold gates g^1, g^2, g^3
        const float b00 = __shfl_xor(a0, 1);
        const float b01 = __shfl_xor(a0, 2);
        const float b02 = __shfl_xor(b00, 2);
        const float b10 = __shfl_xor(a1, 1);
        const float b11 = __shfl_xor(a1, 2);
        const float b12 = __shfl_xor(b10, 2);

        // gates + state + publish (pub lanes: g==0 -> a=zi, b0=zf, b1=zg, b2=zo)
        if (pub) {
            {
                const float ig = fsigm(pv00 + a0);
                const float fg = fsigm(pv01 + b00);
                const float gg = ftanh(pv02 + b01);
                const float og = fsigm(pv03 + b02);
                const float cn = fg * cst0 + ig * gg;
                const float hn = og * ftanh(cn);
                if (tt < len0) { cst0 = cn; hreg0 = hn; pacc0 += hn; }
            }
            {
                const float ig = fsigm(pv10 + a1);
                const float fg = fsigm(pv11 + b10);
                const float gg = ftanh(pv12 + b11);
                const float og = fsigm(pv13 + b12);
                const float cn = fg * cst1 + ig * gg;
                const float hn = og * ftanh(cn);
                if (tt < len1) { cst1 = cn; hreg1 = hn; pacc1 += hn; }
            }
            const unsigned long long tagbits =
                (unsigned long long)(unsigned)(s + 1) << 32;
            const size_t parW = (size_t)((s + 1) & 1) * bufStride;
            __hip_atomic_store(slotW0 + parW,
                               tagbits | (unsigned long long)__float_as_uint(hreg0),
                               __ATOMIC_RELAXED, __HIP_MEMORY_SCOPE_AGENT);
            __hip_atomic_store(slotW1 + parW,
                               tagbits | (unsigned long long)__float_as_uint(hreg1),
                               __ATOMIC_RELAXED, __HIP_MEMORY_SCOPE_AGENT);
        }
        // protect h_sh against next iteration's stage overwrite
        __syncthreads();
    }

    if (pub) {
        pool[(size_t)brow0 * 512 + dir * 256 + cg * 32 + dloc]
            = pacc0 / (float)len0;
        pool[(size_t)(brow0 + 1) * 512 + dir * 256 + cg * 32 + dloc]
            = pacc1 / (float)len1;
    }
}

// ---------------------------------------------------------------------------
// Kernel 4: fc_hidden = relu(pool @ Wfc + bfc); out = fc_hidden @ Wout + bout
// ---------------------------------------------------------------------------
__global__ __launch_bounds__(256)
void k_fc(const float* __restrict__ pool, const float* __restrict__ Wfc,
          const float* __restrict__ bfc, const float* __restrict__ Wout,
          const float* __restrict__ bout, float* __restrict__ out)
{
    __shared__ float p_sh[512];
    __shared__ float red[8];

    const int tid = threadIdx.x;
    const int b   = blockIdx.x;

    p_sh[tid]       = pool[b * 512 + tid];
    p_sh[256 + tid] = pool[b * 512 + 256 + tid];
    __syncthreads();

    float acc = bfc[tid];
#pragma unroll 8
    for (int k = 0; k < 512; ++k)
        acc += p_sh[k] * Wfc[(size_t)k * H_ + tid];
    const float fh = fmaxf(acc, 0.f);

    float p0 = fh * Wout[tid * 2 + 0];
    float p1 = fh * Wout[tid * 2 + 1];
#pragma unroll
    for (int off = 32; off > 0; off >>= 1) {
        p0 += __shfl_down(p0, off);
        p1 += __shfl_down(p1, off);
    }
    const int wave = tid >> 6;
    if ((tid & 63) == 0) { red[wave * 2] = p0; red[wave * 2 + 1] = p1; }
    __syncthreads();
    if (tid == 0) {
        out[b * 2 + 0] = red[0] + red[2] + red[4] + red[6] + bout[0];
        out[b * 2 + 1] = red[1] + red[3] + red[5] + red[7] + bout[1];
    }
}

__global__ void k_sentinel(float* out, int n)
{
    const int i = blockIdx.x * blockDim.x + threadIdx.x;
    if (i < n) out[i] = 1.0e9f;
}

extern "C" void kernel_launch(void* const* d_in, const int* in_sizes, int n_in,
                              void* d_out, int out_size, void* d_ws, size_t ws_size,
                              hipStream_t stream)
{
    const float* emb  = (const float*)d_in[0];
    const float* Win  = (const float*)d_in[1];
    const float* bin  = (const float*)d_in[2];
    const float* Wihf = (const float*)d_in[3];
    const float* Whhf = (const float*)d_in[4];
    const float* blf  = (const float*)d_in[5];
    const float* Wihb = (const float*)d_in[6];
    const float* Whhb = (const float*)d_in[7];
    const float* blb  = (const float*)d_in[8];
    const float* Wfc  = (const float*)d_in[9];
    const float* bfc  = (const float*)d_in[10];
    const float* Wout = (const float*)d_in[11];
    const float* bout = (const float*)d_in[12];
    const int*   x    = (const int*)d_in[13];
    const int*   lens = (const int*)d_in[15];
    float*       out  = (float*)d_out;

    const size_t need = ((size_t)M_ * H_ + 2 * (size_t)M_ * G4_) * sizeof(float);
    if (ws_size < need) {
        hipLaunchKernelGGL(k_sentinel, dim3(1), dim3(64), 0, stream, out, out_size);
        return;
    }

    float* z  = (float*)d_ws;                    // [16384,256] (dead after k2)
    float* Pf = z + (size_t)M_ * H_;             // [16384,1024]
    float* Pb = Pf + (size_t)M_ * G4_;           // [16384,1024]

    // overlay inside z region (init runs after k2 has consumed z)
    unsigned long long* hx   = (unsigned long long*)d_ws;        // packets
    float*              pool = (float*)(hx + HXN);               // [32][512]

    hipLaunchKernelGGL(k_embed_proj, dim3(2, 128), dim3(256), 0, stream,
                       emb, Win, bin, x, z);
    hipLaunchKernelGGL(k_in_proj, dim3(8, 128, 2), dim3(256), 0, stream,
                       z, Wihf, blf, Wihb, blb, Pf, Pb);
    hipLaunchKernelGGL(k_init, dim3(128), dim3(256), 0, stream, hx);
    hipLaunchKernelGGL(k_lstm_persist, dim3(NWG), dim3(THR), 0, stream,
                       Pf, Pb, Whhf, Whhb, lens, hx, pool);
    hipLaunchKernelGGL(k_fc, dim3(32), dim3(256), 0, stream,
                       pool, Wfc, bfc, Wout, bout, out);
}